// Round 10
// baseline (981.577 us; speedup 1.0000x reference)
//
#include <hip/hip_runtime.h>

// RSNN forward: B=128, T=512, IN=128, N=512, OUT=128, fp32 in/out.
// d_out = [vt (128*513*512) | zt (128*513*512) | out (128*512*128)] fp32.
//
// Pipeline:
//  1. jwm:  G = W@J, M = W@Bw (fp32) -> ws
//  2. pack: J->i8 k-split frags (64B slices, 80B-padded LDS at runtime);
//           Bw->bf16 hi/lo; G,M->bf16; zero flags.
//  3. xpd:  D = thr(U) - X@Bw^T -> vt region, SLOT layout (D[b][t] at slot (b,t+1))
//  4. fused (256 WGs x 512 thr, 1/CU):
//     WG b<128 (producer): round-8-proven k-split i8 dot4 recurrence
//       (builtin sdot4 -> AGPR-direct operands, DPP reduce8 + cndmask select),
//       80B-padded s slices (no bank conflicts), z byte -> out region;
//       RELEASE flag every 32 steps (wbl2 makes z8 cross-XCD visible).
//     WG 128+b (consumer, __noinline__): per 64-step chunk, acquire-spin,
//       re-scan z8 -> exact vt/zt floats, out = s@G^T + X@M^T via MFMA,
//       overwriting the z8 chunk in place.

typedef __attribute__((ext_vector_type(8))) short short8x;
typedef __attribute__((ext_vector_type(4))) float f32x4;

// ---- workspace layout (bytes) ----
#define OFF_JQK  (0u)        // J i8 k-split frags: 16384 * 16B = 262144
#define OFF_BWH  (262144u)   // Bw hi bf16 frags: 131072
#define OFF_BWL  (393216u)
#define OFF_G    (524288u)   // G fp32 [128][512] = 262144
#define OFF_M    (786432u)   // M fp32 [128][128] = 65536
#define OFF_GPK  (851968u)   // G bf16 frags: 131072
#define OFF_MPK  (983040u)   // M bf16 frags: 32768
#define OFF_FLG  (1048576u)  // 128 x u32 chunk flags

#define SC_J 640.0f
#define SC_S 166.0f

__device__ __forceinline__ unsigned short f2bf(float f) {
  union { float f; unsigned u; } a; a.f = f;
  unsigned r = a.u + 0x7FFFu + ((a.u >> 16) & 1u);   // RNE bf16
  return (unsigned short)(r >> 16);
}
__device__ __forceinline__ float bf2f(unsigned short h) {
  union { unsigned u; float f; } a; a.u = ((unsigned)h) << 16;
  return a.f;
}
__device__ __forceinline__ float thr_of(float u) {   // spike <=> lamb > thr(u)
  return __builtin_fmaf(4.0f, __logf(u / (1.0f - u)), 0.4f);
}
__device__ __forceinline__ float fast_tanh_pos(float x) {  // x >= 0 here
  const float e2 = __expf(x + x);
  return 1.0f - 2.0f / (e2 + 1.0f);
}
// builtin i8 dot4: operands may live in AGPRs directly (no forced movs).
// Integer math identical to rounds 5-9 (order-invariant).
__device__ __forceinline__ int sdot4(unsigned a, unsigned b, int acc) {
#if __has_builtin(__builtin_amdgcn_sdot4)
  return __builtin_amdgcn_sdot4((int)a, (int)b, acc, false);
#else
  int r;
  asm("v_dot4_i32_i8 %0, %1, %2, %3" : "=v"(r) : "v"(a), "v"(b), "v"(acc));
  return r;
#endif
}
// DPP reduce over the 8 slice-lanes: xor1, xor2, then half-row mirror (=xor7).
template <int CTRL>
__device__ __forceinline__ int dpp_add(int x) {
  return x + __builtin_amdgcn_update_dpp(0, x, CTRL, 0xF, 0xF, true);
}
__device__ __forceinline__ int dpp_reduce8(int x) {
  return dpp_add<0x141>(dpp_add<0x4E>(dpp_add<0xB1>(x)));
}

// ---------------- 1. jwm: G = W@J, M = W@Bw (fp32) ----------------
__launch_bounds__(512)
__global__ void jwm_kernel(const float* __restrict__ J, const float* __restrict__ Bw,
                           const float* __restrict__ W, unsigned char* __restrict__ ws) {
  __shared__ float wrow[512];
  const int o = blockIdx.x;
  const int tid = threadIdx.x;
  wrow[tid] = W[(size_t)o * 512 + tid];
  __syncthreads();
  const int k = tid, i = tid & 127;
  float g = 0.0f, m = 0.0f;
  for (int n = 0; n < 512; ++n) {
    const float wv = wrow[n];
    g = __builtin_fmaf(wv, J[(size_t)n * 512 + k], g);
    m = __builtin_fmaf(wv, Bw[(size_t)n * 128 + i], m);
  }
  ((float*)(ws + OFF_G))[(size_t)o * 512 + k] = g;
  if (tid < 128) ((float*)(ws + OFF_M))[(size_t)o * 128 + i] = m;
}

// ---------------- 2. pack ----------------
// JQK frag f = ((w*8+i)*4 + j)*64 + l : lane l of wave w, neuron
// n = w*64 + (l>>3)*8 + i, slice kap = l&7, bytes J[n][64*kap + 16*j .. +16) i8.
__global__ void pack_kernel(const float* __restrict__ J, const float* __restrict__ Bw,
                            unsigned char* __restrict__ ws) {
  const int id = blockIdx.x * 256 + threadIdx.x;   // grid 136 -> 34816
  if (id < 128) ((unsigned*)(ws + OFF_FLG))[id] = 0u;
  if (id < 16384) {
    const int f = id;
    const int l = f & 63, j = (f >> 6) & 3, i = (f >> 8) & 7, w = f >> 11;
    const int kap = l & 7;
    const int n = w * 64 + (l >> 3) * 8 + i;
    const int k0 = 64 * kap + 16 * j;
    unsigned dw[4];
#pragma unroll
    for (int d = 0; d < 4; ++d) {
      unsigned x = 0;
#pragma unroll
      for (int p = 0; p < 4; ++p) {
        const float jv = J[(size_t)n * 512 + k0 + 4 * d + p];
        int q = __float2int_rn(jv * SC_J);
        q = q > 127 ? 127 : (q < -127 ? -127 : q);
        x |= ((unsigned)(q & 255)) << (8 * p);
      }
      dw[d] = x;
    }
    uint4 out; out.x = dw[0]; out.y = dw[1]; out.z = dw[2]; out.w = dw[3];
    ((uint4*)(ws + OFF_JQK))[f] = out;
  } else if (id < 24576) {
    const int idx = id - 16384;         // (kt*4+g)*512 + n, kt<4
    const int n = idx & 511, kg = idx >> 9, k0 = kg * 8;
    unsigned short* bwh = (unsigned short*)(ws + OFF_BWH);
    unsigned short* bwl = (unsigned short*)(ws + OFF_BWL);
    for (int e = 0; e < 8; ++e) {
      const float x = Bw[(size_t)n * 128 + k0 + e];
      const unsigned short h = f2bf(x);
      bwh[(size_t)idx * 8 + e] = h;
      bwl[(size_t)idx * 8 + e] = f2bf(x - bf2f(h));
    }
  } else if (id < 32768) {
    const int idx = id - 24576;         // (kt*4+g)*128 + o, kt<16
    const int o = idx & 127, kg = idx >> 7, k0 = kg * 8;
    const float* G = (const float*)(ws + OFF_G);
    unsigned short* gpk = (unsigned short*)(ws + OFF_GPK);
    for (int e = 0; e < 8; ++e) gpk[(size_t)idx * 8 + e] = f2bf(G[(size_t)o * 512 + k0 + e]);
  } else {
    const int idx = id - 32768;         // (kt*4+g)*128 + o, kt<4
    const int o = idx & 127, kg = idx >> 7, k0 = kg * 8;
    const float* M = (const float*)(ws + OFF_M);
    unsigned short* mpk = (unsigned short*)(ws + OFF_MPK);
    for (int e = 0; e < 8; ++e) mpk[(size_t)idx * 8 + e] = f2bf(M[(size_t)o * 128 + k0 + e]);
  }
}

// ---------------- 3. xpd: D = thr(U) - X@Bw^T, SLOT layout ----------------
__launch_bounds__(256)
__global__ void xpd_kernel(const float* __restrict__ X, const float* __restrict__ U,
                           const unsigned char* __restrict__ ws, float* __restrict__ Dbuf) {
  __shared__ short Ah[64 * 136];
  __shared__ short Al[64 * 136];
  const unsigned short* bwh = (const unsigned short*)(ws + OFF_BWH);
  const unsigned short* bwl = (const unsigned short*)(ws + OFF_BWL);
  const int m0 = blockIdx.x * 64;
  const int n0 = blockIdx.y * 64;
  const int tid = threadIdx.x;
  for (int i = tid; i < 64 * 32; i += 256) {
    const int r = i >> 5, kq = i & 31;
    const float4 x4 = *(const float4*)(X + (size_t)(m0 + r) * 128 + kq * 4);
    short4 h4, l4; unsigned short h;
    h = f2bf(x4.x); h4.x = (short)h; l4.x = (short)f2bf(x4.x - bf2f(h));
    h = f2bf(x4.y); h4.y = (short)h; l4.y = (short)f2bf(x4.y - bf2f(h));
    h = f2bf(x4.z); h4.z = (short)h; l4.z = (short)f2bf(x4.z - bf2f(h));
    h = f2bf(x4.w); h4.w = (short)h; l4.w = (short)f2bf(x4.w - bf2f(h));
    *(short4*)(&Ah[r * 136 + kq * 4]) = h4;
    *(short4*)(&Al[r * 136 + kq * 4]) = l4;
  }
  __syncthreads();
  const int w = tid >> 6, l = tid & 63, lhi = l >> 4, llo = l & 15;
  const int rowA = 16 * w + llo;
  f32x4 a0 = {0,0,0,0}, a1 = {0,0,0,0}, a2 = {0,0,0,0}, a3 = {0,0,0,0};
#pragma unroll
  for (int kt = 0; kt < 4; ++kt) {
    const short8x ah = *(const short8x*)(&Ah[rowA * 136 + kt * 32 + lhi * 8]);
    const short8x al = *(const short8x*)(&Al[rowA * 136 + kt * 32 + lhi * 8]);
#define XT(TI, ACC) { \
    const size_t bi = ((size_t)((kt * 4 + lhi) * 512 + n0 + TI * 16 + llo)) * 8; \
    const short8x bh = *(const short8x*)(bwh + bi); \
    const short8x bl = *(const short8x*)(bwl + bi); \
    ACC = __builtin_amdgcn_mfma_f32_16x16x32_bf16(ah, bh, ACC, 0, 0, 0); \
    ACC = __builtin_amdgcn_mfma_f32_16x16x32_bf16(al, bh, ACC, 0, 0, 0); \
    ACC = __builtin_amdgcn_mfma_f32_16x16x32_bf16(ah, bl, ACC, 0, 0, 0); }
    XT(0, a0) XT(1, a1) XT(2, a2) XT(3, a3)
#undef XT
  }
  const int n = n0 + llo;
#pragma unroll
  for (int r = 0; r < 4; ++r) {
    const int bt = m0 + 16 * w + lhi * 4 + r;
    const int bb = bt >> 9, tt = bt & 511;
    const float* urow = U + (size_t)bt * 512;
    float* drow = Dbuf + ((size_t)bb * 513 + tt + 1) * 512;   // slot (b, t+1)
    drow[n]      = thr_of(urow[n])      - a0[r];
    drow[n + 16] = thr_of(urow[n + 16]) - a1[r];
    drow[n + 32] = thr_of(urow[n + 32]) - a2[r];
    drow[n + 48] = thr_of(urow[n + 48]) - a3[r];
  }
}

// ---------------- consumer (separate regalloc via noinline) ----------------
__device__ __noinline__ void consumer_path(
    const float* __restrict__ X, const unsigned char* __restrict__ ws,
    float* __restrict__ vt, float* __restrict__ zt, float* __restrict__ op,
    unsigned* __restrict__ flags, unsigned* zl, unsigned short* sl,
    unsigned short* xl, int b) {
  const int tid = threadIdx.x;
  const int w = tid >> 6, l = tid & 63, lhi = l >> 4, llo = l & 15;
  const unsigned short* gpk = (const unsigned short*)(ws + OFF_GPK);
  const unsigned short* mpk = (const unsigned short*)(ws + OFF_MPK);
  const unsigned char* z8 = (const unsigned char*)op;
  const unsigned* flagp = flags + b;

  float v = 0.0f;
  unsigned zprev = 0u;
  vt[((size_t)b * 513) * 512 + tid] = 0.0f;   // t=0 slots
  zt[((size_t)b * 513) * 512 + tid] = 0.0f;

  for (int c = 0; c < 8; ++c) {
    {
      const unsigned tgt = (unsigned)(64 * (c + 1));
      long guard = 0;
      while (__hip_atomic_load(flagp, __ATOMIC_ACQUIRE,
                               __HIP_MEMORY_SCOPE_AGENT) < tgt) {
        __builtin_amdgcn_s_sleep(8);
        if (++guard > 200000000L) break;   // bug -> wrong answer, not hang
      }
    }
    const uint4* src = (const uint4*)(z8 + (size_t)b * 262144 + (size_t)c * 32768);
#pragma unroll
    for (int i = 0; i < 4; ++i) ((uint4*)zl)[i * 512 + tid] = src[i * 512 + tid];
#pragma unroll
    for (int i = 0; i < 4; ++i) {
      const int idx = i * 512 + tid;
      const int r = idx >> 5, c4 = (idx & 31) * 4;
      const float4 x4 = *(const float4*)(X + ((size_t)b * 512 + c * 64 + r) * 128 + c4);
      short4 h4;
      h4.x = (short)f2bf(x4.x); h4.y = (short)f2bf(x4.y);
      h4.z = (short)f2bf(x4.z); h4.w = (short)f2bf(x4.w);
      *(short4*)(xl + r * 136 + c4) = h4;
    }
    __syncthreads();
    const unsigned char* zb = (const unsigned char*)zl;
    float* vrow = vt + ((size_t)b * 513 + c * 64 + 1) * 512 + tid;
    float* zrow = zt + ((size_t)b * 513 + c * 64 + 1) * 512 + tid;
#pragma unroll 8
    for (int tl = 0; tl < 64; ++tl) {
      v = __builtin_fmaf(0.9f, v, zprev ? 0.1f : 0.0f);
      const unsigned z = zb[tl * 512 + tid];
      vrow[(size_t)tl * 512] = v;
      zrow[(size_t)tl * 512] = z ? 1.0f : 0.0f;
      sl[tl * 520 + tid] = f2bf(fast_tanh_pos(v));
      zprev = z;
    }
    __syncthreads();
    const int m = w >> 1, oh = (w & 1) * 4;
    f32x4 a0 = {0,0,0,0}, a1 = {0,0,0,0}, a2 = {0,0,0,0}, a3 = {0,0,0,0};
#pragma unroll
    for (int kt = 0; kt < 16; ++kt) {
      const short8x A = *(const short8x*)(sl + (m * 16 + llo) * 520 + kt * 32 + lhi * 8);
#define GT(TI, ACC) { \
      const short8x B = *(const short8x*)(gpk + ((size_t)((kt * 4 + lhi) * 128 + (oh + TI) * 16 + llo)) * 8); \
      ACC = __builtin_amdgcn_mfma_f32_16x16x32_bf16(A, B, ACC, 0, 0, 0); }
      GT(0, a0) GT(1, a1) GT(2, a2) GT(3, a3)
#undef GT
    }
#pragma unroll
    for (int kt = 0; kt < 4; ++kt) {
      const short8x A = *(const short8x*)(xl + (m * 16 + llo) * 136 + kt * 32 + lhi * 8);
#define MT(TI, ACC) { \
      const short8x B = *(const short8x*)(mpk + ((size_t)((kt * 4 + lhi) * 128 + (oh + TI) * 16 + llo)) * 8); \
      ACC = __builtin_amdgcn_mfma_f32_16x16x32_bf16(A, B, ACC, 0, 0, 0); }
      MT(0, a0) MT(1, a1) MT(2, a2) MT(3, a3)
#undef MT
    }
    float* obase = op + ((size_t)b * 512 + c * 64 + m * 16 + lhi * 4) * 128 + llo;
#pragma unroll
    for (int r = 0; r < 4; ++r) {
      float* orow = obase + (size_t)r * 128;
      orow[(oh + 0) * 16] = a0[r];
      orow[(oh + 1) * 16] = a1[r];
      orow[(oh + 2) * 16] = a2[r];
      orow[(oh + 3) * 16] = a3[r];
    }
    __syncthreads();
  }
}

// ---------------- 4. fused producer/consumer ----------------
__launch_bounds__(512, 1)
__global__ void fused_kernel(const float* __restrict__ X, unsigned char* __restrict__ ws,
                             float* __restrict__ vt, float* __restrict__ zt,
                             float* __restrict__ op) {
  // producer LDS: s int8, 8 slices x 80B padded (bank phases 4 apart)
  __shared__ __align__(16) unsigned char s_sm[2][640];
  // consumer LDS
  __shared__ unsigned zl[8192];
  __shared__ unsigned short sl[64 * 520];
  __shared__ unsigned short xl[64 * 136];
  unsigned* flags = (unsigned*)(ws + OFF_FLG);
  const int tid = threadIdx.x;

  if (blockIdx.x >= 128) {
    consumer_path(X, ws, vt, zt, op, flags, zl, sl, xl, (int)blockIdx.x - 128);
    return;
  }
  // ================= producer: batch b recurrence (round-8 internals) =========
  const int b = blockIdx.x;
  const int w = tid >> 6, l = tid & 63;
  const int kap = l & 7, kap80 = kap * 80;

  uint4 jr[8][4];
#pragma unroll
  for (int i = 0; i < 8; ++i)
#pragma unroll
    for (int j = 0; j < 4; ++j) {
      const unsigned char* p = ws + OFF_JQK +
          (size_t)(((w * 8 + i) * 4 + j) * 64 + l) * 16;
      asm volatile("global_load_dwordx4 %0, %1, off" : "=v"(jr[i][j]) : "v"(p));
    }
  asm volatile("s_waitcnt vmcnt(0)" ::: "memory");

  const float SC = 1.0f / (SC_J * SC_S);
  const float* Dp = vt + ((size_t)b * 513 + 1) * 512 + tid;   // D slot base
  unsigned char* zwg = (unsigned char*)op + (size_t)b * 262144 + tid;
  unsigned* flagp = flags + b;

  float dc[8], dnx[8];
#pragma unroll
  for (int i = 0; i < 8; ++i) dc[i] = Dp[(size_t)i * 512];

  unsigned zprev = 0u;
  float v0 = 0.0f, v1 = 0.1f;
  unsigned q0 = (unsigned)__float2int_rn(fast_tanh_pos(v0) * SC_S);
  unsigned q1 = (unsigned)__float2int_rn(fast_tanh_pos(v1) * SC_S);

  for (int c = 0; c < 64; ++c) {       // 64 chunks x 8 steps
    const int t0 = c * 8;
#pragma unroll
    for (int i = 0; i < 8; ++i) dnx[i] = Dp[(size_t)(t0 + 8 + i) * 512];
#pragma unroll
    for (int i = 0; i < 8; ++i) {
      const int t = t0 + i;
      const unsigned q = zprev ? q1 : q0;
      const float v = zprev ? v1 : v0;
      s_sm[t & 1][w * 80 + l] = (unsigned char)q;
      asm volatile("s_waitcnt lgkmcnt(0)\n\ts_barrier" ::: "memory");
      v0 = 0.9f * v; v1 = v0 + 0.1f;
      q0 = (unsigned)__float2int_rn(fast_tanh_pos(v0) * SC_S);
      q1 = (unsigned)__float2int_rn(fast_tanh_pos(v1) * SC_S);
      const unsigned char* sb = &s_sm[t & 1][0];
      const uint4 s0 = *(const uint4*)(sb + kap80);
      const uint4 s1 = *(const uint4*)(sb + kap80 + 16);
      const uint4 s2 = *(const uint4*)(sb + kap80 + 32);
      const uint4 s3 = *(const uint4*)(sb + kap80 + 48);
      int a0 = 0, a1 = 0, a2 = 0, a3 = 0, a4 = 0, a5 = 0, a6 = 0, a7 = 0;
#define DOT(AI, I) \
      AI = sdot4(jr[I][0].x, s0.x, AI); AI = sdot4(jr[I][0].y, s0.y, AI); \
      AI = sdot4(jr[I][0].z, s0.z, AI); AI = sdot4(jr[I][0].w, s0.w, AI); \
      AI = sdot4(jr[I][1].x, s1.x, AI); AI = sdot4(jr[I][1].y, s1.y, AI); \
      AI = sdot4(jr[I][1].z, s1.z, AI); AI = sdot4(jr[I][1].w, s1.w, AI); \
      AI = sdot4(jr[I][2].x, s2.x, AI); AI = sdot4(jr[I][2].y, s2.y, AI); \
      AI = sdot4(jr[I][2].z, s2.z, AI); AI = sdot4(jr[I][2].w, s2.w, AI); \
      AI = sdot4(jr[I][3].x, s3.x, AI); AI = sdot4(jr[I][3].y, s3.y, AI); \
      AI = sdot4(jr[I][3].z, s3.z, AI); AI = sdot4(jr[I][3].w, s3.w, AI);
      DOT(a0, 0) DOT(a1, 1) DOT(a2, 2) DOT(a3, 3)
      DOT(a4, 4) DOT(a5, 5) DOT(a6, 6) DOT(a7, 7)
#undef DOT
      a0 = dpp_reduce8(a0); a1 = dpp_reduce8(a1);
      a2 = dpp_reduce8(a2); a3 = dpp_reduce8(a3);
      a4 = dpp_reduce8(a4); a5 = dpp_reduce8(a5);
      a6 = dpp_reduce8(a6); a7 = dpp_reduce8(a7);
      // select own neuron's lambda: in-group index = l&7 = kap
      const int q01 = (l & 1) ? a1 : a0;
      const int q23 = (l & 1) ? a3 : a2;
      const int q45 = (l & 1) ? a5 : a4;
      const int q67 = (l & 1) ? a7 : a6;
      const int r0 = (l & 2) ? q23 : q01;
      const int r1 = (l & 2) ? q67 : q45;
      const int accv = (l & 4) ? r1 : r0;
      const float lam = (float)accv * SC;
      const unsigned z = (lam > dc[i]) ? 1u : 0u;
      zwg[(size_t)t * 512] = (unsigned char)z;
      zprev = z;
    }
    if ((c & 3) == 3)   // release: drains z8 stores + wbl2 -> cross-XCD visible
      __hip_atomic_store(flagp, (unsigned)(t0 + 8), __ATOMIC_RELEASE,
                         __HIP_MEMORY_SCOPE_AGENT);
#pragma unroll
    for (int i = 0; i < 8; ++i) dc[i] = dnx[i];
  }
}

extern "C" void kernel_launch(void* const* d_in, const int* in_sizes, int n_in,
                              void* d_out, int out_size, void* d_ws, size_t ws_size,
                              hipStream_t stream) {
  const float* X  = (const float*)d_in[0];   // inputs [128,512,128]
  const float* U  = (const float*)d_in[1];   // rand_u [128,512,512]
  const float* J  = (const float*)d_in[2];   // [512,512]
  const float* Bw = (const float*)d_in[3];   // [512,128]
  const float* W  = (const float*)d_in[4];   // [128,512]
  float* vt = (float*)d_out;
  float* zt = vt + (size_t)128 * 513 * 512;
  float* op = vt + (size_t)2 * 128 * 513 * 512;
  unsigned char* ws = (unsigned char*)d_ws;

  jwm_kernel<<<128, 512, 0, stream>>>(J, Bw, W, ws);
  pack_kernel<<<136, 256, 0, stream>>>(J, Bw, ws);
  xpd_kernel<<<dim3(1024, 8), 256, 0, stream>>>(X, U, ws, vt);   // D -> vt slots
  fused_kernel<<<256, 512, 0, stream>>>(X, ws, vt, zt, op);
}

// Round 11
// 803.209 us; speedup vs baseline: 1.2221x; 1.2221x over previous
//
#include <hip/hip_runtime.h>

// RSNN forward: B=128, T=512, IN=128, N=512, OUT=128, fp32 in/out.
// d_out = [vt (128*513*512) | zt (128*513*512) | out (128*512*128)] fp32.
//
// Pipeline:
//  1. jwm:  G = W@J, M = W@Bw (fp32) -> ws
//  2. pack: J->i8 k-split frags; Bw->bf16 hi/lo; G,M->bf16 frags -> ws
//  3. xpd:  D = thr(U) - X@Bw^T -> vt region, SLOT layout (D[b][t] at slot (b,t+1))
//  4. fused (128 WGs x 512 thr, 1 batch/WG, ZERO cross-WG traffic):
//     per step: k-split i8 dot4 recurrence (round-8 internals: builtin sdot4,
//     DPP reduce8, cndmask select; 80B-padded s slices); thread tid = neuron n
//     stores v -> vt slot, z -> zt slot, bf16 tanh(v) -> LDS sl tile.
//     Every 64 steps: stage X chunk, MFMA out[64t x 128o] = s@G^T + X@M^T.
//     No flags, no spinning, no L2-invalidate storm (round-10 lesson).

typedef __attribute__((ext_vector_type(8))) short short8x;
typedef __attribute__((ext_vector_type(4))) float f32x4;

// ---- workspace layout (bytes) ----
#define OFF_JQK  (0u)        // J i8 k-split frags: 16384 * 16B = 262144
#define OFF_BWH  (262144u)   // Bw hi bf16 frags: 131072
#define OFF_BWL  (393216u)
#define OFF_G    (524288u)   // G fp32 [128][512] = 262144
#define OFF_M    (786432u)   // M fp32 [128][128] = 65536
#define OFF_GPK  (851968u)   // G bf16 frags: 131072
#define OFF_MPK  (983040u)   // M bf16 frags: 32768

#define SC_J 640.0f
#define SC_S 166.0f

__device__ __forceinline__ unsigned short f2bf(float f) {
  union { float f; unsigned u; } a; a.f = f;
  unsigned r = a.u + 0x7FFFu + ((a.u >> 16) & 1u);   // RNE bf16
  return (unsigned short)(r >> 16);
}
__device__ __forceinline__ float bf2f(unsigned short h) {
  union { unsigned u; float f; } a; a.u = ((unsigned)h) << 16;
  return a.f;
}
__device__ __forceinline__ float thr_of(float u) {   // spike <=> lamb > thr(u)
  return __builtin_fmaf(4.0f, __logf(u / (1.0f - u)), 0.4f);
}
__device__ __forceinline__ float fast_tanh_pos(float x) {  // x >= 0 here
  const float e2 = __expf(x + x);
  return 1.0f - 2.0f / (e2 + 1.0f);
}
// builtin i8 dot4 (AGPR-direct operands ok). Integer math order-invariant;
// identical trajectories to rounds 5-10.
__device__ __forceinline__ int sdot4(unsigned a, unsigned b, int acc) {
#if __has_builtin(__builtin_amdgcn_sdot4)
  return __builtin_amdgcn_sdot4((int)a, (int)b, acc, false);
#else
  int r;
  asm("v_dot4_i32_i8 %0, %1, %2, %3" : "=v"(r) : "v"(a), "v"(b), "v"(acc));
  return r;
#endif
}
template <int CTRL>
__device__ __forceinline__ int dpp_add(int x) {
  return x + __builtin_amdgcn_update_dpp(0, x, CTRL, 0xF, 0xF, true);
}
__device__ __forceinline__ int dpp_reduce8(int x) {
  return dpp_add<0x141>(dpp_add<0x4E>(dpp_add<0xB1>(x)));
}

// ---------------- 1. jwm: G = W@J, M = W@Bw (fp32) ----------------
__launch_bounds__(512)
__global__ void jwm_kernel(const float* __restrict__ J, const float* __restrict__ Bw,
                           const float* __restrict__ W, unsigned char* __restrict__ ws) {
  __shared__ float wrow[512];
  const int o = blockIdx.x;
  const int tid = threadIdx.x;
  wrow[tid] = W[(size_t)o * 512 + tid];
  __syncthreads();
  const int k = tid, i = tid & 127;
  float g = 0.0f, m = 0.0f;
  for (int n = 0; n < 512; ++n) {
    const float wv = wrow[n];
    g = __builtin_fmaf(wv, J[(size_t)n * 512 + k], g);
    m = __builtin_fmaf(wv, Bw[(size_t)n * 128 + i], m);
  }
  ((float*)(ws + OFF_G))[(size_t)o * 512 + k] = g;
  if (tid < 128) ((float*)(ws + OFF_M))[(size_t)o * 128 + i] = m;
}

// ---------------- 2. pack ----------------
// JQK frag f = ((w*8+i)*4 + j)*64 + l : lane l of wave w, neuron
// n = w*64 + (l>>3)*8 + i, slice kap = l&7, bytes J[n][64*kap + 16*j .. +16) i8.
__global__ void pack_kernel(const float* __restrict__ J, const float* __restrict__ Bw,
                            unsigned char* __restrict__ ws) {
  const int id = blockIdx.x * 256 + threadIdx.x;   // grid 136 -> 34816
  if (id < 16384) {
    const int f = id;
    const int l = f & 63, j = (f >> 6) & 3, i = (f >> 8) & 7, w = f >> 11;
    const int kap = l & 7;
    const int n = w * 64 + (l >> 3) * 8 + i;
    const int k0 = 64 * kap + 16 * j;
    unsigned dw[4];
#pragma unroll
    for (int d = 0; d < 4; ++d) {
      unsigned x = 0;
#pragma unroll
      for (int p = 0; p < 4; ++p) {
        const float jv = J[(size_t)n * 512 + k0 + 4 * d + p];
        int q = __float2int_rn(jv * SC_J);
        q = q > 127 ? 127 : (q < -127 ? -127 : q);
        x |= ((unsigned)(q & 255)) << (8 * p);
      }
      dw[d] = x;
    }
    uint4 out; out.x = dw[0]; out.y = dw[1]; out.z = dw[2]; out.w = dw[3];
    ((uint4*)(ws + OFF_JQK))[f] = out;
  } else if (id < 24576) {
    const int idx = id - 16384;         // (kt*4+g)*512 + n, kt<4
    const int n = idx & 511, kg = idx >> 9, k0 = kg * 8;
    unsigned short* bwh = (unsigned short*)(ws + OFF_BWH);
    unsigned short* bwl = (unsigned short*)(ws + OFF_BWL);
    for (int e = 0; e < 8; ++e) {
      const float x = Bw[(size_t)n * 128 + k0 + e];
      const unsigned short h = f2bf(x);
      bwh[(size_t)idx * 8 + e] = h;
      bwl[(size_t)idx * 8 + e] = f2bf(x - bf2f(h));
    }
  } else if (id < 32768) {
    const int idx = id - 24576;         // (kt*4+g)*128 + o, kt<16
    const int o = idx & 127, kg = idx >> 7, k0 = kg * 8;
    const float* G = (const float*)(ws + OFF_G);
    unsigned short* gpk = (unsigned short*)(ws + OFF_GPK);
    for (int e = 0; e < 8; ++e) gpk[(size_t)idx * 8 + e] = f2bf(G[(size_t)o * 512 + k0 + e]);
  } else {
    const int idx = id - 32768;         // (kt*4+g)*128 + o, kt<4
    const int o = idx & 127, kg = idx >> 7, k0 = kg * 8;
    const float* M = (const float*)(ws + OFF_M);
    unsigned short* mpk = (unsigned short*)(ws + OFF_MPK);
    for (int e = 0; e < 8; ++e) mpk[(size_t)idx * 8 + e] = f2bf(M[(size_t)o * 128 + k0 + e]);
  }
}

// ---------------- 3. xpd: D = thr(U) - X@Bw^T, SLOT layout ----------------
__launch_bounds__(256)
__global__ void xpd_kernel(const float* __restrict__ X, const float* __restrict__ U,
                           const unsigned char* __restrict__ ws, float* __restrict__ Dbuf) {
  __shared__ short Ah[64 * 136];
  __shared__ short Al[64 * 136];
  const unsigned short* bwh = (const unsigned short*)(ws + OFF_BWH);
  const unsigned short* bwl = (const unsigned short*)(ws + OFF_BWL);
  const int m0 = blockIdx.x * 64;
  const int n0 = blockIdx.y * 64;
  const int tid = threadIdx.x;
  for (int i = tid; i < 64 * 32; i += 256) {
    const int r = i >> 5, kq = i & 31;
    const float4 x4 = *(const float4*)(X + (size_t)(m0 + r) * 128 + kq * 4);
    short4 h4, l4; unsigned short h;
    h = f2bf(x4.x); h4.x = (short)h; l4.x = (short)f2bf(x4.x - bf2f(h));
    h = f2bf(x4.y); h4.y = (short)h; l4.y = (short)f2bf(x4.y - bf2f(h));
    h = f2bf(x4.z); h4.z = (short)h; l4.z = (short)f2bf(x4.z - bf2f(h));
    h = f2bf(x4.w); h4.w = (short)h; l4.w = (short)f2bf(x4.w - bf2f(h));
    *(short4*)(&Ah[r * 136 + kq * 4]) = h4;
    *(short4*)(&Al[r * 136 + kq * 4]) = l4;
  }
  __syncthreads();
  const int w = tid >> 6, l = tid & 63, lhi = l >> 4, llo = l & 15;
  const int rowA = 16 * w + llo;
  f32x4 a0 = {0,0,0,0}, a1 = {0,0,0,0}, a2 = {0,0,0,0}, a3 = {0,0,0,0};
#pragma unroll
  for (int kt = 0; kt < 4; ++kt) {
    const short8x ah = *(const short8x*)(&Ah[rowA * 136 + kt * 32 + lhi * 8]);
    const short8x al = *(const short8x*)(&Al[rowA * 136 + kt * 32 + lhi * 8]);
#define XT(TI, ACC) { \
    const size_t bi = ((size_t)((kt * 4 + lhi) * 512 + n0 + TI * 16 + llo)) * 8; \
    const short8x bh = *(const short8x*)(bwh + bi); \
    const short8x bl = *(const short8x*)(bwl + bi); \
    ACC = __builtin_amdgcn_mfma_f32_16x16x32_bf16(ah, bh, ACC, 0, 0, 0); \
    ACC = __builtin_amdgcn_mfma_f32_16x16x32_bf16(al, bh, ACC, 0, 0, 0); \
    ACC = __builtin_amdgcn_mfma_f32_16x16x32_bf16(ah, bl, ACC, 0, 0, 0); }
    XT(0, a0) XT(1, a1) XT(2, a2) XT(3, a3)
#undef XT
  }
  const int n = n0 + llo;
#pragma unroll
  for (int r = 0; r < 4; ++r) {
    const int bt = m0 + 16 * w + lhi * 4 + r;
    const int bb = bt >> 9, tt = bt & 511;
    const float* urow = U + (size_t)bt * 512;
    float* drow = Dbuf + ((size_t)bb * 513 + tt + 1) * 512;   // slot (b, t+1)
    drow[n]      = thr_of(urow[n])      - a0[r];
    drow[n + 16] = thr_of(urow[n + 16]) - a1[r];
    drow[n + 32] = thr_of(urow[n + 32]) - a2[r];
    drow[n + 48] = thr_of(urow[n + 48]) - a3[r];
  }
}

// ---------------- 4. fused: recurrence + direct vt/zt + per-chunk out MFMA ----------------
__launch_bounds__(512, 1)
__global__ void fused_kernel(const float* __restrict__ X, unsigned char* __restrict__ ws,
                             float* __restrict__ vt, float* __restrict__ zt,
                             float* __restrict__ op) {
  __shared__ __align__(16) unsigned char s_sm[2][640];   // 8 slices x 80B padded
  __shared__ unsigned short sl[64 * 520];                // s bf16 [64 t][512 n]
  __shared__ unsigned short xl[64 * 136];                // X bf16 [64 t][128 i]
  const int b = blockIdx.x;            // 1 batch per WG
  const int tid = threadIdx.x;         // neuron n = tid
  const int w = tid >> 6, l = tid & 63;
  const int kap = l & 7, kap80 = kap * 80;
  const int lhi = l >> 4, llo = l & 15;

  // J frags (round-8 layout), pinned via volatile asm loads
  uint4 jr[8][4];
#pragma unroll
  for (int i = 0; i < 8; ++i)
#pragma unroll
    for (int j = 0; j < 4; ++j) {
      const unsigned char* p = ws + OFF_JQK +
          (size_t)(((w * 8 + i) * 4 + j) * 64 + l) * 16;
      asm volatile("global_load_dwordx4 %0, %1, off" : "=v"(jr[i][j]) : "v"(p));
    }
  asm volatile("s_waitcnt vmcnt(0)" ::: "memory");

  const unsigned short* gpk = (const unsigned short*)(ws + OFF_GPK);
  const unsigned short* mpk = (const unsigned short*)(ws + OFF_MPK);
  const float SC = 1.0f / (SC_J * SC_S);

  // t=0 slots
  vt[((size_t)b * 513) * 512 + tid] = 0.0f;
  zt[((size_t)b * 513) * 512 + tid] = 0.0f;

  const float* Dp = vt + ((size_t)b * 513 + 1) * 512 + tid;   // D slot base (read)
  float* vtw = vt + ((size_t)b * 513 + 1) * 512 + tid;        // v slot base (write)
  float* ztw = zt + ((size_t)b * 513 + 1) * 512 + tid;

  float dc[8], dnx[8];
#pragma unroll
  for (int i = 0; i < 8; ++i) dc[i] = Dp[(size_t)i * 512];

  unsigned zprev = 0u;
  float v0 = 0.0f, v1 = 0.1f;
  float sf0 = fast_tanh_pos(v0), sf1 = fast_tanh_pos(v1);
  unsigned q0 = (unsigned)__float2int_rn(sf0 * SC_S);
  unsigned q1 = (unsigned)__float2int_rn(sf1 * SC_S);

  for (int C = 0; C < 8; ++C) {        // 8 big chunks x 64 steps
#pragma unroll 1
    for (int c = 0; c < 8; ++c) {      // 8 sub-chunks x 8 steps
      const int t0 = C * 64 + c * 8;
      // next sub-chunk D prefetch (tail over-read stays in d_out; values unused)
#pragma unroll
      for (int i = 0; i < 8; ++i) dnx[i] = Dp[(size_t)(t0 + 8 + i) * 512];
#pragma unroll
      for (int i = 0; i < 8; ++i) {
        const int t = t0 + i;
        const int tl = t & 63;
        const unsigned q = zprev ? q1 : q0;
        const float v = zprev ? v1 : v0;
        const float sf = zprev ? sf1 : sf0;
        s_sm[t & 1][w * 80 + l] = (unsigned char)q;
        sl[tl * 520 + tid] = f2bf(sf);
        asm volatile("s_waitcnt lgkmcnt(0)\n\ts_barrier" ::: "memory");
        // next-step candidates (overlap ds_read latency)
        v0 = 0.9f * v; v1 = v0 + 0.1f;
        sf0 = fast_tanh_pos(v0); sf1 = fast_tanh_pos(v1);
        q0 = (unsigned)__float2int_rn(sf0 * SC_S);
        q1 = (unsigned)__float2int_rn(sf1 * SC_S);
        // this lane's 64B s-slice
        const unsigned char* sb = &s_sm[t & 1][0];
        const uint4 s0 = *(const uint4*)(sb + kap80);
        const uint4 s1 = *(const uint4*)(sb + kap80 + 16);
        const uint4 s2 = *(const uint4*)(sb + kap80 + 32);
        const uint4 s3 = *(const uint4*)(sb + kap80 + 48);
        int a0 = 0, a1 = 0, a2 = 0, a3 = 0, a4 = 0, a5 = 0, a6 = 0, a7 = 0;
#define DOT(AI, I) \
        AI = sdot4(jr[I][0].x, s0.x, AI); AI = sdot4(jr[I][0].y, s0.y, AI); \
        AI = sdot4(jr[I][0].z, s0.z, AI); AI = sdot4(jr[I][0].w, s0.w, AI); \
        AI = sdot4(jr[I][1].x, s1.x, AI); AI = sdot4(jr[I][1].y, s1.y, AI); \
        AI = sdot4(jr[I][1].z, s1.z, AI); AI = sdot4(jr[I][1].w, s1.w, AI); \
        AI = sdot4(jr[I][2].x, s2.x, AI); AI = sdot4(jr[I][2].y, s2.y, AI); \
        AI = sdot4(jr[I][2].z, s2.z, AI); AI = sdot4(jr[I][2].w, s2.w, AI); \
        AI = sdot4(jr[I][3].x, s3.x, AI); AI = sdot4(jr[I][3].y, s3.y, AI); \
        AI = sdot4(jr[I][3].z, s3.z, AI); AI = sdot4(jr[I][3].w, s3.w, AI);
        DOT(a0, 0) DOT(a1, 1) DOT(a2, 2) DOT(a3, 3)
        DOT(a4, 4) DOT(a5, 5) DOT(a6, 6) DOT(a7, 7)
#undef DOT
        a0 = dpp_reduce8(a0); a1 = dpp_reduce8(a1);
        a2 = dpp_reduce8(a2); a3 = dpp_reduce8(a3);
        a4 = dpp_reduce8(a4); a5 = dpp_reduce8(a5);
        a6 = dpp_reduce8(a6); a7 = dpp_reduce8(a7);
        const int q01 = (l & 1) ? a1 : a0;
        const int q23 = (l & 1) ? a3 : a2;
        const int q45 = (l & 1) ? a5 : a4;
        const int q67 = (l & 1) ? a7 : a6;
        const int r0 = (l & 2) ? q23 : q01;
        const int r1 = (l & 2) ? q67 : q45;
        const int accv = (l & 4) ? r1 : r0;
        const float lam = (float)accv * SC;
        const unsigned z = (lam > dc[i]) ? 1u : 0u;
        // vt store: addr depends on z (asm) so it cannot be hoisted above the
        // dc compare -> the D load of this slot is provably complete (no WAR).
        unsigned zzero;
        asm("v_and_b32 %0, 0, %1" : "=v"(zzero) : "v"(z));
        vtw[(size_t)t * 512 + zzero] = v;
        ztw[(size_t)t * 512] = z ? 1.0f : 0.0f;
        zprev = z;
      }
#pragma unroll
      for (int i = 0; i < 8; ++i) dc[i] = dnx[i];
    }
    // ---- chunk boundary: stage X, then out-MFMA for this 64-step window ----
    float4 xr[4];
#pragma unroll
    for (int i = 0; i < 4; ++i) {
      const int idx = i * 512 + tid;
      const int r = idx >> 5, c4 = (idx & 31) * 4;
      xr[i] = *(const float4*)(X + ((size_t)b * 512 + C * 64 + r) * 128 + c4);
    }
#pragma unroll
    for (int i = 0; i < 4; ++i) {
      const int idx = i * 512 + tid;
      const int r = idx >> 5, c4 = (idx & 31) * 4;
      short4 h4;
      h4.x = (short)f2bf(xr[i].x); h4.y = (short)f2bf(xr[i].y);
      h4.z = (short)f2bf(xr[i].z); h4.w = (short)f2bf(xr[i].w);
      *(short4*)(xl + r * 136 + c4) = h4;
    }
    __syncthreads();   // sl complete (per-step barriers) + xl visible
    const int m = w >> 1, oh = (w & 1) * 4;
    f32x4 a0 = {0,0,0,0}, a1 = {0,0,0,0}, a2 = {0,0,0,0}, a3 = {0,0,0,0};
#pragma unroll
    for (int kt = 0; kt < 16; ++kt) {
      const short8x A = *(const short8x*)(sl + (m * 16 + llo) * 520 + kt * 32 + lhi * 8);
#define GT(TI, ACC) { \
      const short8x B = *(const short8x*)(gpk + ((size_t)((kt * 4 + lhi) * 128 + (oh + TI) * 16 + llo)) * 8); \
      ACC = __builtin_amdgcn_mfma_f32_16x16x32_bf16(A, B, ACC, 0, 0, 0); }
      GT(0, a0) GT(1, a1) GT(2, a2) GT(3, a3)
#undef GT
    }
#pragma unroll
    for (int kt = 0; kt < 4; ++kt) {
      const short8x A = *(const short8x*)(xl + (m * 16 + llo) * 136 + kt * 32 + lhi * 8);
#define MT(TI, ACC) { \
      const short8x B = *(const short8x*)(mpk + ((size_t)((kt * 4 + lhi) * 128 + (oh + TI) * 16 + llo)) * 8); \
      ACC = __builtin_amdgcn_mfma_f32_16x16x32_bf16(A, B, ACC, 0, 0, 0); }
      MT(0, a0) MT(1, a1) MT(2, a2) MT(3, a3)
#undef MT
    }
    float* obase = op + ((size_t)b * 512 + C * 64 + m * 16 + lhi * 4) * 128 + llo;
#pragma unroll
    for (int r = 0; r < 4; ++r) {
      float* orow = obase + (size_t)r * 128;
      orow[(oh + 0) * 16] = a0[r];
      orow[(oh + 1) * 16] = a1[r];
      orow[(oh + 2) * 16] = a2[r];
      orow[(oh + 3) * 16] = a3[r];
    }
    __syncthreads();   // protect sl/xl before next chunk overwrites
  }
}

extern "C" void kernel_launch(void* const* d_in, const int* in_sizes, int n_in,
                              void* d_out, int out_size, void* d_ws, size_t ws_size,
                              hipStream_t stream) {
  const float* X  = (const float*)d_in[0];   // inputs [128,512,128]
  const float* U  = (const float*)d_in[1];   // rand_u [128,512,512]
  const float* J  = (const float*)d_in[2];   // [512,512]
  const float* Bw = (const float*)d_in[3];   // [512,128]
  const float* W  = (const float*)d_in[4];   // [128,512]
  float* vt = (float*)d_out;
  float* zt = vt + (size_t)128 * 513 * 512;
  float* op = vt + (size_t)2 * 128 * 513 * 512;
  unsigned char* ws = (unsigned char*)d_ws;

  jwm_kernel<<<128, 512, 0, stream>>>(J, Bw, W, ws);
  pack_kernel<<<136, 256, 0, stream>>>(J, Bw, ws);
  xpd_kernel<<<dim3(1024, 8), 256, 0, stream>>>(X, U, ws, vt);   // D -> vt slots
  fused_kernel<<<128, 512, 0, stream>>>(X, ws, vt, zt, op);
}

// Round 12
// 680.537 us; speedup vs baseline: 1.4424x; 1.1803x over previous
//
#include <hip/hip_runtime.h>

// RSNN forward: B=128, T=512, IN=128, N=512, OUT=128, fp32 in/out.
// d_out = [vt (128*513*512) | zt (128*513*512) | out (128*512*128)] fp32.
//
// Pipeline:
//  1. jwm:  G = W@J, M = W@Bw (fp32) -> ws
//  2. pack: J->i8 k-split frags; Bw->bf16 hi/lo; G,M->bf16 frags -> ws
//  3. xpd:  D = thr(U) - X@Bw^T -> vt region, SLOT layout (D[b][t] at slot (b,t+1))
//  4. recur (128 WGs x 512 thr, 1 batch/WG, zero cross-WG traffic):
//     round-8 k-split i8 dot4 step (builtin sdot4, DPP reduce8, cndmask select,
//     80B-padded s slices). v/z accumulate in REGISTERS per 8-step sub-chunk,
//     bulk-stored (16 clean stride-512 dwords) after all D uses; one
//     z-derived opaque-zero on the store base enforces WAR order in HW.
//     D-read and v-write views passed as separate __restrict__ params so the
//     compiler emits no defensive vmcnt drains (round-11 lesson).
//  5. outk (grid 1024, all CUs): read vt slots -> s=tanh(v) bf16 tile + X tile
//     -> MFMA out[64t x 128o] = s@G^T + X@M^T. No z8, no flags, no spinning.

typedef __attribute__((ext_vector_type(8))) short short8x;
typedef __attribute__((ext_vector_type(4))) float f32x4;

// ---- workspace layout (bytes) ----
#define OFF_JQK  (0u)        // J i8 k-split frags: 16384 * 16B = 262144
#define OFF_BWH  (262144u)   // Bw hi bf16 frags: 131072
#define OFF_BWL  (393216u)
#define OFF_G    (524288u)   // G fp32 [128][512] = 262144
#define OFF_M    (786432u)   // M fp32 [128][128] = 65536
#define OFF_GPK  (851968u)   // G bf16 frags: 131072
#define OFF_MPK  (983040u)   // M bf16 frags: 32768

#define SC_J 640.0f
#define SC_S 166.0f

__device__ __forceinline__ unsigned short f2bf(float f) {
  union { float f; unsigned u; } a; a.f = f;
  unsigned r = a.u + 0x7FFFu + ((a.u >> 16) & 1u);   // RNE bf16
  return (unsigned short)(r >> 16);
}
__device__ __forceinline__ float bf2f(unsigned short h) {
  union { unsigned u; float f; } a; a.u = ((unsigned)h) << 16;
  return a.f;
}
__device__ __forceinline__ float thr_of(float u) {   // spike <=> lamb > thr(u)
  return __builtin_fmaf(4.0f, __logf(u / (1.0f - u)), 0.4f);
}
__device__ __forceinline__ float fast_tanh_pos(float x) {  // x >= 0 here
  const float e2 = __expf(x + x);
  return 1.0f - 2.0f / (e2 + 1.0f);
}
// builtin i8 dot4 (AGPR-direct operands ok). Integer math order-invariant;
// identical trajectories to rounds 5-11.
__device__ __forceinline__ int sdot4(unsigned a, unsigned b, int acc) {
#if __has_builtin(__builtin_amdgcn_sdot4)
  return __builtin_amdgcn_sdot4((int)a, (int)b, acc, false);
#else
  int r;
  asm("v_dot4_i32_i8 %0, %1, %2, %3" : "=v"(r) : "v"(a), "v"(b), "v"(acc));
  return r;
#endif
}
template <int CTRL>
__device__ __forceinline__ int dpp_add(int x) {
  return x + __builtin_amdgcn_update_dpp(0, x, CTRL, 0xF, 0xF, true);
}
__device__ __forceinline__ int dpp_reduce8(int x) {
  return dpp_add<0x141>(dpp_add<0x4E>(dpp_add<0xB1>(x)));
}

// ---------------- 1. jwm: G = W@J, M = W@Bw (fp32) ----------------
__launch_bounds__(512)
__global__ void jwm_kernel(const float* __restrict__ J, const float* __restrict__ Bw,
                           const float* __restrict__ W, unsigned char* __restrict__ ws) {
  __shared__ float wrow[512];
  const int o = blockIdx.x;
  const int tid = threadIdx.x;
  wrow[tid] = W[(size_t)o * 512 + tid];
  __syncthreads();
  const int k = tid, i = tid & 127;
  float g = 0.0f, m = 0.0f;
  for (int n = 0; n < 512; ++n) {
    const float wv = wrow[n];
    g = __builtin_fmaf(wv, J[(size_t)n * 512 + k], g);
    m = __builtin_fmaf(wv, Bw[(size_t)n * 128 + i], m);
  }
  ((float*)(ws + OFF_G))[(size_t)o * 512 + k] = g;
  if (tid < 128) ((float*)(ws + OFF_M))[(size_t)o * 128 + i] = m;
}

// ---------------- 2. pack ----------------
// JQK frag f = ((w*8+i)*4 + j)*64 + l : lane l of wave w, neuron
// n = w*64 + (l>>3)*8 + i, slice kap = l&7, bytes J[n][64*kap + 16*j .. +16) i8.
__global__ void pack_kernel(const float* __restrict__ J, const float* __restrict__ Bw,
                            unsigned char* __restrict__ ws) {
  const int id = blockIdx.x * 256 + threadIdx.x;   // grid 136 -> 34816
  if (id < 16384) {
    const int f = id;
    const int l = f & 63, j = (f >> 6) & 3, i = (f >> 8) & 7, w = f >> 11;
    const int kap = l & 7;
    const int n = w * 64 + (l >> 3) * 8 + i;
    const int k0 = 64 * kap + 16 * j;
    unsigned dw[4];
#pragma unroll
    for (int d = 0; d < 4; ++d) {
      unsigned x = 0;
#pragma unroll
      for (int p = 0; p < 4; ++p) {
        const float jv = J[(size_t)n * 512 + k0 + 4 * d + p];
        int q = __float2int_rn(jv * SC_J);
        q = q > 127 ? 127 : (q < -127 ? -127 : q);
        x |= ((unsigned)(q & 255)) << (8 * p);
      }
      dw[d] = x;
    }
    uint4 out; out.x = dw[0]; out.y = dw[1]; out.z = dw[2]; out.w = dw[3];
    ((uint4*)(ws + OFF_JQK))[f] = out;
  } else if (id < 24576) {
    const int idx = id - 16384;         // (kt*4+g)*512 + n, kt<4
    const int n = idx & 511, kg = idx >> 9, k0 = kg * 8;
    unsigned short* bwh = (unsigned short*)(ws + OFF_BWH);
    unsigned short* bwl = (unsigned short*)(ws + OFF_BWL);
    for (int e = 0; e < 8; ++e) {
      const float x = Bw[(size_t)n * 128 + k0 + e];
      const unsigned short h = f2bf(x);
      bwh[(size_t)idx * 8 + e] = h;
      bwl[(size_t)idx * 8 + e] = f2bf(x - bf2f(h));
    }
  } else if (id < 32768) {
    const int idx = id - 24576;         // (kt*4+g)*128 + o, kt<16
    const int o = idx & 127, kg = idx >> 7, k0 = kg * 8;
    const float* G = (const float*)(ws + OFF_G);
    unsigned short* gpk = (unsigned short*)(ws + OFF_GPK);
    for (int e = 0; e < 8; ++e) gpk[(size_t)idx * 8 + e] = f2bf(G[(size_t)o * 512 + k0 + e]);
  } else {
    const int idx = id - 32768;         // (kt*4+g)*128 + o, kt<4
    const int o = idx & 127, kg = idx >> 7, k0 = kg * 8;
    const float* M = (const float*)(ws + OFF_M);
    unsigned short* mpk = (unsigned short*)(ws + OFF_MPK);
    for (int e = 0; e < 8; ++e) mpk[(size_t)idx * 8 + e] = f2bf(M[(size_t)o * 128 + k0 + e]);
  }
}

// ---------------- 3. xpd: D = thr(U) - X@Bw^T, SLOT layout ----------------
__launch_bounds__(256)
__global__ void xpd_kernel(const float* __restrict__ X, const float* __restrict__ U,
                           const unsigned char* __restrict__ ws, float* __restrict__ Dbuf) {
  __shared__ short Ah[64 * 136];
  __shared__ short Al[64 * 136];
  const unsigned short* bwh = (const unsigned short*)(ws + OFF_BWH);
  const unsigned short* bwl = (const unsigned short*)(ws + OFF_BWL);
  const int m0 = blockIdx.x * 64;
  const int n0 = blockIdx.y * 64;
  const int tid = threadIdx.x;
  for (int i = tid; i < 64 * 32; i += 256) {
    const int r = i >> 5, kq = i & 31;
    const float4 x4 = *(const float4*)(X + (size_t)(m0 + r) * 128 + kq * 4);
    short4 h4, l4; unsigned short h;
    h = f2bf(x4.x); h4.x = (short)h; l4.x = (short)f2bf(x4.x - bf2f(h));
    h = f2bf(x4.y); h4.y = (short)h; l4.y = (short)f2bf(x4.y - bf2f(h));
    h = f2bf(x4.z); h4.z = (short)h; l4.z = (short)f2bf(x4.z - bf2f(h));
    h = f2bf(x4.w); h4.w = (short)h; l4.w = (short)f2bf(x4.w - bf2f(h));
    *(short4*)(&Ah[r * 136 + kq * 4]) = h4;
    *(short4*)(&Al[r * 136 + kq * 4]) = l4;
  }
  __syncthreads();
  const int w = tid >> 6, l = tid & 63, lhi = l >> 4, llo = l & 15;
  const int rowA = 16 * w + llo;
  f32x4 a0 = {0,0,0,0}, a1 = {0,0,0,0}, a2 = {0,0,0,0}, a3 = {0,0,0,0};
#pragma unroll
  for (int kt = 0; kt < 4; ++kt) {
    const short8x ah = *(const short8x*)(&Ah[rowA * 136 + kt * 32 + lhi * 8]);
    const short8x al = *(const short8x*)(&Al[rowA * 136 + kt * 32 + lhi * 8]);
#define XT(TI, ACC) { \
    const size_t bi = ((size_t)((kt * 4 + lhi) * 512 + n0 + TI * 16 + llo)) * 8; \
    const short8x bh = *(const short8x*)(bwh + bi); \
    const short8x bl = *(const short8x*)(bwl + bi); \
    ACC = __builtin_amdgcn_mfma_f32_16x16x32_bf16(ah, bh, ACC, 0, 0, 0); \
    ACC = __builtin_amdgcn_mfma_f32_16x16x32_bf16(al, bh, ACC, 0, 0, 0); \
    ACC = __builtin_amdgcn_mfma_f32_16x16x32_bf16(ah, bl, ACC, 0, 0, 0); }
    XT(0, a0) XT(1, a1) XT(2, a2) XT(3, a3)
#undef XT
  }
  const int n = n0 + llo;
#pragma unroll
  for (int r = 0; r < 4; ++r) {
    const int bt = m0 + 16 * w + lhi * 4 + r;
    const int bb = bt >> 9, tt = bt & 511;
    const float* urow = U + (size_t)bt * 512;
    float* drow = Dbuf + ((size_t)bb * 513 + tt + 1) * 512;   // slot (b, t+1)
    drow[n]      = thr_of(urow[n])      - a0[r];
    drow[n + 16] = thr_of(urow[n + 16]) - a1[r];
    drow[n + 32] = thr_of(urow[n + 32]) - a2[r];
    drow[n + 48] = thr_of(urow[n + 48]) - a3[r];
  }
}

// ---------------- 4. recur: 128 WGs x 512 thr, 1 batch/WG ----------------
// Dv (D read) and vtw (v write) both point into vt; declared restrict so the
// compiler schedules freely. True WAR order (store slot t+1 after its D was
// consumed) is enforced by the z-derived opaque-zero on the store base.
__launch_bounds__(512, 1)
__global__ void recur_kernel(const unsigned char* __restrict__ ws,
                             const float* __restrict__ Dv,
                             float* __restrict__ vtw, float* __restrict__ ztw) {
  __shared__ __align__(16) unsigned char s_sm[2][640];   // 8 slices x 80B padded
  const int b = blockIdx.x;            // 1 batch per WG
  const int tid = threadIdx.x;         // neuron n = tid
  const int w = tid >> 6, l = tid & 63;
  const int kap = l & 7, kap80 = kap * 80;

  // J frags (round-8 layout), pinned via volatile asm loads
  uint4 jr[8][4];
#pragma unroll
  for (int i = 0; i < 8; ++i)
#pragma unroll
    for (int j = 0; j < 4; ++j) {
      const unsigned char* p = ws + OFF_JQK +
          (size_t)(((w * 8 + i) * 4 + j) * 64 + l) * 16;
      asm volatile("global_load_dwordx4 %0, %1, off" : "=v"(jr[i][j]) : "v"(p));
    }
  asm volatile("s_waitcnt vmcnt(0)" ::: "memory");

  const float SC = 1.0f / (SC_J * SC_S);
  // t=0 slots
  vtw[((size_t)b * 513) * 512 + tid] = 0.0f;
  ztw[((size_t)b * 513) * 512 + tid] = 0.0f;

  const float* Dp = Dv + ((size_t)b * 513 + 1) * 512 + tid;   // D slot base
  float* vbase = vtw + ((size_t)b * 513 + 1) * 512 + tid;     // v slot base
  float* zbase = ztw + ((size_t)b * 513 + 1) * 512 + tid;

  float dc[8], dnx[8];
#pragma unroll
  for (int i = 0; i < 8; ++i) dc[i] = Dp[(size_t)i * 512];

  unsigned zprev = 0u;
  float v0 = 0.0f, v1 = 0.1f;
  unsigned q0 = (unsigned)__float2int_rn(fast_tanh_pos(v0) * SC_S);
  unsigned q1 = (unsigned)__float2int_rn(fast_tanh_pos(v1) * SC_S);

  for (int c = 0; c < 64; ++c) {       // 64 sub-chunks x 8 steps
    const int t0 = c * 8;
    // next sub-chunk D prefetch (tail over-read stays inside d_out; unused)
#pragma unroll
    for (int i = 0; i < 8; ++i) dnx[i] = Dp[(size_t)(t0 + 8 + i) * 512];
    float v_arr[8];
    unsigned zbits = 0u;
#pragma unroll
    for (int i = 0; i < 8; ++i) {
      const int t = t0 + i;
      const unsigned q = zprev ? q1 : q0;
      const float v = zprev ? v1 : v0;
      v_arr[i] = v;
      s_sm[t & 1][w * 80 + l] = (unsigned char)q;
      asm volatile("s_waitcnt lgkmcnt(0)\n\ts_barrier" ::: "memory");
      // next-step candidates (overlap ds_read latency)
      v0 = 0.9f * v; v1 = v0 + 0.1f;
      q0 = (unsigned)__float2int_rn(fast_tanh_pos(v0) * SC_S);
      q1 = (unsigned)__float2int_rn(fast_tanh_pos(v1) * SC_S);
      // this lane's 64B s-slice
      const unsigned char* sb = &s_sm[t & 1][0];
      const uint4 s0 = *(const uint4*)(sb + kap80);
      const uint4 s1 = *(const uint4*)(sb + kap80 + 16);
      const uint4 s2 = *(const uint4*)(sb + kap80 + 32);
      const uint4 s3 = *(const uint4*)(sb + kap80 + 48);
      int a0 = 0, a1 = 0, a2 = 0, a3 = 0, a4 = 0, a5 = 0, a6 = 0, a7 = 0;
#define DOT(AI, I) \
      AI = sdot4(jr[I][0].x, s0.x, AI); AI = sdot4(jr[I][0].y, s0.y, AI); \
      AI = sdot4(jr[I][0].z, s0.z, AI); AI = sdot4(jr[I][0].w, s0.w, AI); \
      AI = sdot4(jr[I][1].x, s1.x, AI); AI = sdot4(jr[I][1].y, s1.y, AI); \
      AI = sdot4(jr[I][1].z, s1.z, AI); AI = sdot4(jr[I][1].w, s1.w, AI); \
      AI = sdot4(jr[I][2].x, s2.x, AI); AI = sdot4(jr[I][2].y, s2.y, AI); \
      AI = sdot4(jr[I][2].z, s2.z, AI); AI = sdot4(jr[I][2].w, s2.w, AI); \
      AI = sdot4(jr[I][3].x, s3.x, AI); AI = sdot4(jr[I][3].y, s3.y, AI); \
      AI = sdot4(jr[I][3].z, s3.z, AI); AI = sdot4(jr[I][3].w, s3.w, AI);
      DOT(a0, 0) DOT(a1, 1) DOT(a2, 2) DOT(a3, 3)
      DOT(a4, 4) DOT(a5, 5) DOT(a6, 6) DOT(a7, 7)
#undef DOT
      a0 = dpp_reduce8(a0); a1 = dpp_reduce8(a1);
      a2 = dpp_reduce8(a2); a3 = dpp_reduce8(a3);
      a4 = dpp_reduce8(a4); a5 = dpp_reduce8(a5);
      a6 = dpp_reduce8(a6); a7 = dpp_reduce8(a7);
      const int q01 = (l & 1) ? a1 : a0;
      const int q23 = (l & 1) ? a3 : a2;
      const int q45 = (l & 1) ? a5 : a4;
      const int q67 = (l & 1) ? a7 : a6;
      const int r0 = (l & 2) ? q23 : q01;
      const int r1 = (l & 2) ? q67 : q45;
      const int accv = (l & 4) ? r1 : r0;
      const float lam = (float)accv * SC;
      const unsigned z = (lam > dc[i]) ? 1u : 0u;
      zbits |= z << i;
      zprev = z;
    }
    // ---- bulk store: after ALL dc uses of this sub-chunk. zprev depends on
    // dc[7] -> opaque-zero from it orders the stores after the D waitcnts.
    unsigned zzero;
    asm("v_and_b32 %0, 0, %1" : "=v"(zzero) : "v"(zprev));
    float* vst = vbase + (size_t)t0 * 512 + zzero;
    float* zst = zbase + (size_t)t0 * 512;
#pragma unroll
    for (int i = 0; i < 8; ++i) {
      vst[(size_t)i * 512] = v_arr[i];
      zst[(size_t)i * 512] = ((zbits >> i) & 1u) ? 1.0f : 0.0f;
    }
#pragma unroll
    for (int i = 0; i < 8; ++i) dc[i] = dnx[i];
  }
}

// ---------------- 5. outk: out = tanh(vt)@G^T + X@M^T ----------------
// Grid 1024 x 512 thr; block handles 64 bt rows. Reads final vt slots.
__launch_bounds__(512)
__global__ void outk_kernel(const float* __restrict__ X, const float* __restrict__ vt,
                            const unsigned char* __restrict__ ws,
                            float* __restrict__ op) {
  __shared__ unsigned short sl[64 * 520];    // s bf16 [64 t][512 n]
  __shared__ unsigned short xl[64 * 136];    // X bf16 [64 t][128 i]
  const int m0 = blockIdx.x * 64;            // bt rows
  const int tid = threadIdx.x;
  const int w = tid >> 6, l = tid & 63, lhi = l >> 4, llo = l & 15;
  const unsigned short* gpk = (const unsigned short*)(ws + OFF_GPK);
  const unsigned short* mpk = (const unsigned short*)(ws + OFF_MPK);

  // stage s = tanh(v) from vt slots (coalesced; v >= 0 always)
#pragma unroll 4
  for (int r = 0; r < 64; ++r) {
    const int bt = m0 + r, b = bt >> 9, t = bt & 511;
    const float v = vt[((size_t)b * 513 + t + 1) * 512 + tid];
    sl[r * 520 + tid] = f2bf(fast_tanh_pos(v));
  }
  // stage X
#pragma unroll
  for (int i = 0; i < 16; ++i) {
    const int idx = i * 512 + tid;
    const int r = idx >> 7, c = idx & 127;
    const int bt = m0 + r;
    xl[r * 136 + c] = f2bf(X[(size_t)bt * 128 + c]);
  }
  __syncthreads();
  // MFMA: C[64 t][128 o]; wave w: m-tile = w>>1, o-tiles (w&1)*4 + 0..3
  const int m = w >> 1, oh = (w & 1) * 4;
  f32x4 a0 = {0,0,0,0}, a1 = {0,0,0,0}, a2 = {0,0,0,0}, a3 = {0,0,0,0};
#pragma unroll
  for (int kt = 0; kt < 16; ++kt) {
    const short8x A = *(const short8x*)(sl + (m * 16 + llo) * 520 + kt * 32 + lhi * 8);
#define GT(TI, ACC) { \
    const short8x B = *(const short8x*)(gpk + ((size_t)((kt * 4 + lhi) * 128 + (oh + TI) * 16 + llo)) * 8); \
    ACC = __builtin_amdgcn_mfma_f32_16x16x32_bf16(A, B, ACC, 0, 0, 0); }
    GT(0, a0) GT(1, a1) GT(2, a2) GT(3, a3)
#undef GT
  }
#pragma unroll
  for (int kt = 0; kt < 4; ++kt) {
    const short8x A = *(const short8x*)(xl + (m * 16 + llo) * 136 + kt * 32 + lhi * 8);
#define MT(TI, ACC) { \
    const short8x B = *(const short8x*)(mpk + ((size_t)((kt * 4 + lhi) * 128 + (oh + TI) * 16 + llo)) * 8); \
    ACC = __builtin_amdgcn_mfma_f32_16x16x32_bf16(A, B, ACC, 0, 0, 0); }
    MT(0, a0) MT(1, a1) MT(2, a2) MT(3, a3)
#undef MT
  }
  float* obase = op + ((size_t)(m0 + m * 16 + lhi * 4)) * 128 + llo;
#pragma unroll
  for (int r = 0; r < 4; ++r) {
    float* orow = obase + (size_t)r * 128;
    orow[(oh + 0) * 16] = a0[r];
    orow[(oh + 1) * 16] = a1[r];
    orow[(oh + 2) * 16] = a2[r];
    orow[(oh + 3) * 16] = a3[r];
  }
}

extern "C" void kernel_launch(void* const* d_in, const int* in_sizes, int n_in,
                              void* d_out, int out_size, void* d_ws, size_t ws_size,
                              hipStream_t stream) {
  const float* X  = (const float*)d_in[0];   // inputs [128,512,128]
  const float* U  = (const float*)d_in[1];   // rand_u [128,512,512]
  const float* J  = (const float*)d_in[2];   // [512,512]
  const float* Bw = (const float*)d_in[3];   // [512,128]
  const float* W  = (const float*)d_in[4];   // [128,512]
  float* vt = (float*)d_out;
  float* zt = vt + (size_t)128 * 513 * 512;
  float* op = vt + (size_t)2 * 128 * 513 * 512;
  unsigned char* ws = (unsigned char*)d_ws;

  jwm_kernel<<<128, 512, 0, stream>>>(J, Bw, W, ws);
  pack_kernel<<<136, 256, 0, stream>>>(J, Bw, ws);
  xpd_kernel<<<dim3(1024, 8), 256, 0, stream>>>(X, U, ws, vt);   // D -> vt slots
  recur_kernel<<<128, 512, 0, stream>>>(ws, vt, vt, zt);
  outk_kernel<<<1024, 512, 0, stream>>>(X, vt, ws, op);
}